// Round 2
// baseline (23.084 us; speedup 1.0000x reference)
//
#include <hip/hip_runtime.h>
#include <math.h>

// probs/targets: (32,1,512,512) fp32
#define NS 32               // samples
#define NELEM 262144        // elements per sample
#define PB 64               // partial blocks per sample
#define CHUNK (NELEM / PB)  // 4096 elements per block
#define TPB 256             // threads per block (4 waves)
// per-thread: CHUNK/TPB = 16 elements = 4 float4 pairs

#define SP (NS * PB)        // 2048 partial sets
#define OFF_S1   0
#define OFF_S2   (SP * 1)
#define OFF_DOT  (SP * 2)
#define OFF_MX   (SP * 3)
#define OFF_CGT  (SP * 4)   // int: count(p > 0.5)
#define OFF_CNT  (SP * 5)   // int: multiplicity of running max
#define OFF_GT   (SP * 6)   // int: count(p > 0.5 at running-max positions)

__device__ __forceinline__ void combine_max(float& mx, int& cnt, int& gt,
                                            float mx2, int cnt2, int gt2) {
    if (mx2 > mx) { mx = mx2; cnt = cnt2; gt = gt2; }
    else if (mx2 == mx) { cnt += cnt2; gt += gt2; }
}

__global__ __launch_bounds__(TPB) void k_partial(const float* __restrict__ probs,
                                                 const float* __restrict__ tgts,
                                                 float* __restrict__ wsf,
                                                 int* __restrict__ wsi) {
    const int b = blockIdx.x;
    const int s = b >> 6;        // sample
    const int c = b & (PB - 1);  // chunk
    const size_t base = (size_t)s * NELEM + (size_t)c * CHUNK;
    const float4* __restrict__ p4 = (const float4*)(probs + base);
    const float4* __restrict__ t4 = (const float4*)(tgts + base);
    const int t = threadIdx.x;

    // Front-load all data: 8 back-to-back dwordx4 loads -> max MLP
    float4 pv[4], tv[4];
#pragma unroll
    for (int k = 0; k < 4; ++k) {
        pv[k] = p4[t + k * TPB];
        tv[k] = t4[t + k * TPB];
    }

    // 4 independent accumulator sets (one per float4 lane) -> breaks the
    // serial max-compare dependency chain
    float s1[4] = {0.f, 0.f, 0.f, 0.f};
    float s2[4] = {0.f, 0.f, 0.f, 0.f};
    float dt[4] = {0.f, 0.f, 0.f, 0.f};
    float mx[4] = {-INFINITY, -INFINITY, -INFINITY, -INFINITY};
    int cgt[4] = {0, 0, 0, 0}, cnt[4] = {0, 0, 0, 0}, gt[4] = {0, 0, 0, 0};

#pragma unroll
    for (int k = 0; k < 4; ++k) {
        const float pc[4] = {pv[k].x, pv[k].y, pv[k].z, pv[k].w};
        const float tc[4] = {tv[k].x, tv[k].y, tv[k].z, tv[k].w};
#pragma unroll
        for (int j = 0; j < 4; ++j) {
            const float p = pc[j], q = tc[j];
            const int b1 = (p > 0.5f) ? 1 : 0;
            s1[j] += p;
            s2[j] += q;
            dt[j] = fmaf(p, q, dt[j]);
            cgt[j] += b1;
            if (q > mx[j])       { mx[j] = q; cnt[j] = 1; gt[j] = b1; }
            else if (q == mx[j]) { cnt[j] += 1; gt[j] += b1; }
        }
    }

    // merge the 4 component sets
    float rs1 = s1[0] + s1[1] + s1[2] + s1[3];
    float rs2 = s2[0] + s2[1] + s2[2] + s2[3];
    float rdt = dt[0] + dt[1] + dt[2] + dt[3];
    int rcgt = cgt[0] + cgt[1] + cgt[2] + cgt[3];
    float rmx = mx[0]; int rcnt = cnt[0], rgt = gt[0];
#pragma unroll
    for (int j = 1; j < 4; ++j) combine_max(rmx, rcnt, rgt, mx[j], cnt[j], gt[j]);

    // 64-lane wave xor-butterfly reduction
#pragma unroll
    for (int off = 32; off; off >>= 1) {
        rs1  += __shfl_xor(rs1, off);
        rs2  += __shfl_xor(rs2, off);
        rdt  += __shfl_xor(rdt, off);
        rcgt += __shfl_xor(rcgt, off);
        float m2 = __shfl_xor(rmx, off);
        int   c2 = __shfl_xor(rcnt, off);
        int   g2 = __shfl_xor(rgt, off);
        combine_max(rmx, rcnt, rgt, m2, c2, g2);
    }

    // cross-wave via LDS (4 waves)
    __shared__ float ls1[4], ls2[4], ldt[4], lmx[4];
    __shared__ int   lcg[4], lcn[4], lgt[4];
    const int w = t >> 6, lane = t & 63;
    if (lane == 0) {
        ls1[w] = rs1; ls2[w] = rs2; ldt[w] = rdt; lmx[w] = rmx;
        lcg[w] = rcgt; lcn[w] = rcnt; lgt[w] = rgt;
    }
    __syncthreads();
    if (t == 0) {
#pragma unroll
        for (int w2 = 1; w2 < TPB / 64; ++w2) {
            rs1 += ls1[w2]; rs2 += ls2[w2]; rdt += ldt[w2]; rcgt += lcg[w2];
            combine_max(rmx, rcnt, rgt, lmx[w2], lcn[w2], lgt[w2]);
        }
        wsf[OFF_S1  + b] = rs1;
        wsf[OFF_S2  + b] = rs2;
        wsf[OFF_DOT + b] = rdt;
        wsf[OFF_MX  + b] = rmx;
        wsi[OFF_CGT + b] = rcgt;
        wsi[OFF_CNT + b] = rcnt;
        wsi[OFF_GT  + b] = rgt;
    }
}

// Fused per-sample finalize + mean: 1 block, 1024 threads (16 waves).
// Wave w reduces samples 2w and 2w+1 (64 partials each, one per lane);
// then wave 0 means the 32 scores.
__global__ __launch_bounds__(1024) void k_final(const float* __restrict__ wsf,
                                                const int* __restrict__ wsi,
                                                float* __restrict__ out) {
    __shared__ float scores[NS];
    const int t = threadIdx.x;
    const int w = t >> 6, lane = t & 63;

#pragma unroll
    for (int r = 0; r < 2; ++r) {
        const int s = w * 2 + r;
        const int idx = s * PB + lane;

        float s1  = wsf[OFF_S1  + idx];
        float s2  = wsf[OFF_S2  + idx];
        float dot = wsf[OFF_DOT + idx];
        float mx  = wsf[OFF_MX  + idx];
        int   cgt = wsi[OFF_CGT + idx];
        int   cnt = wsi[OFF_CNT + idx];
        int   gt  = wsi[OFF_GT  + idx];

#pragma unroll
        for (int off = 32; off; off >>= 1) {
            s1  += __shfl_xor(s1, off);
            s2  += __shfl_xor(s2, off);
            dot += __shfl_xor(dot, off);
            cgt += __shfl_xor(cgt, off);
            float m2 = __shfl_xor(mx, off);
            int   c2 = __shfl_xor(cnt, off);
            int   g2 = __shfl_xor(gt, off);
            combine_max(mx, cnt, gt, m2, c2, g2);
        }

        if (lane == 0) {
            // corr = count(m1<=0.5) - cnt_at_max + 2*gt_at_max (tie-safe)
            const int cle = NELEM - cgt;
            const long long corr = (long long)cle - (long long)cnt + 2LL * (long long)gt;
            float score = 2.0f * (dot + 1.0f) / (s1 + s2 + 1.0f);
            if (corr == 1) score = 1.0f;  // acc == 1.0 branch (shape[1] == 1)
            scores[s] = 1.0f - score;
        }
    }

    __syncthreads();
    if (t < 64) {
        float v = (t < NS) ? scores[t] : 0.0f;
#pragma unroll
        for (int off = 32; off; off >>= 1) v += __shfl_xor(v, off);
        if (t == 0) out[0] = v * (1.0f / (float)NS);
    }
}

extern "C" void kernel_launch(void* const* d_in, const int* in_sizes, int n_in,
                              void* d_out, int out_size, void* d_ws, size_t ws_size,
                              hipStream_t stream) {
    const float* probs = (const float*)d_in[0];
    const float* tgts  = (const float*)d_in[1];
    float* wsf = (float*)d_ws;
    int*   wsi = (int*)d_ws;
    float* out = (float*)d_out;

    k_partial<<<NS * PB, TPB, 0, stream>>>(probs, tgts, wsf, wsi);
    k_final<<<1, 1024, 0, stream>>>(wsf, wsi, out);
}